// Round 1
// baseline (1671.984 us; speedup 1.0000x reference)
//
#include <hip/hip_runtime.h>
#include <stdint.h>

// ============================================================================
// Motion_Relation_Mining — bit-exact replication of the JAX (CPU) reference.
//
// VARIANT AXES (flip on failure, one per round):
//   NAN_POLICY_A : 1 = NaN maha selected FIRST in top-169 (total-order sort
//                  semantics; XLA sort+slice / GPU path).
//                  0 = (future) libstdc++ partial_sort plain-`>` emulation.
//   TANH_FMA     : 1 = Eigen/XLA tanh rational poly evaluated with FMA
//                  (AVX2 pmadd). 0 = plain mul+add.
//   (reduce orders: all 100-elem and C/r reductions are SEQUENTIAL, matching
//   XLA CPU's scalar reduce emission; vectorized-8 variant is a future axis.)
// ============================================================================
#define NAN_POLICY_A 1
#define TANH_FMA 1

typedef unsigned int u32;
typedef unsigned long long u64;

// sizes
#define BB 4
#define TT 8
#define CC 16
#define HWN 65536              // H*W = 256*256
#define NF 7
#define FRAME 1048576LL        // C*H*W
#define NELF 7340032.0f        // nf*C*H*W per batch (exact in f32)
#define NPAIR 28               // B*nf
#define SEG 65536              // G*rs*rs spatial positions

// ws layout (bytes)
#define WS_MM 0                // u32[4][6]: xt_min,xt_max,x1_min,x1_max,p_min,p_max (encoded)
#define WS_CORR 128            // float[4]
#define WS_HIST 512            // u32[4][3][100]  (0..99 xt, 100..199 xt1, 200..299 joint)
#define WS_TOP 8192            // int[28][64]
#define WS_MAG 16384           // float[28][65536]
#define WS_NEED (16384 + 28LL*65536*4)

__device__ __forceinline__ u32 encf(float f) {
  u32 u = __float_as_uint(f);
  return (u & 0x80000000u) ? ~u : (u | 0x80000000u);
}
__device__ __forceinline__ float decf(u32 e) {
  u32 u = (e & 0x80000000u) ? (e ^ 0x80000000u) : ~e;
  return __uint_as_float(u);
}

__global__ void k_init(u32* ws) {
  int t = threadIdx.x;
  if (t < 24) ws[t] = ((t & 1) == 0) ? 0xFFFFFFFFu : 0u;  // even=min slots, odd=max slots
  for (int i = t; i < 1200; i += 256) ws[(WS_HIST / 4) + i] = 0u;
}

// ---- pass 1: per-batch min/max of x_t, x_t1, x_t*x_t1 (exact; encoded u32 atomics)
__global__ void k_minmax(const float* __restrict__ x, u32* __restrict__ mm) {
  const long long blk_base = (long long)blockIdx.x * 4096;     // pair-element index
  const int b = (int)(blk_base / 7340032LL);
  const int t = (int)((blk_base % 7340032LL) / FRAME);
  const long long base = ((long long)(b * TT + t)) * FRAME;
  const long long w0 = blk_base % FRAME;
  u32 mn0 = 0xFFFFFFFFu, mx0 = 0u, mn1 = 0xFFFFFFFFu, mx1 = 0u, mnp = 0xFFFFFFFFu, mxp = 0u;
  for (int k = 0; k < 16; ++k) {
    long long w = w0 + threadIdx.x + (k << 8);
    float a = x[base + w];
    float c = x[base + FRAME + w];
    float p = __fmul_rn(a, c);
    u32 ea = encf(a), ec = encf(c), ep = encf(p);
    mn0 = min(mn0, ea); mx0 = max(mx0, ea);
    mn1 = min(mn1, ec); mx1 = max(mx1, ec);
    mnp = min(mnp, ep); mxp = max(mxp, ep);
  }
  __shared__ u32 sm[6][256];
  int tid = threadIdx.x;
  sm[0][tid] = mn0; sm[1][tid] = mx0; sm[2][tid] = mn1;
  sm[3][tid] = mx1; sm[4][tid] = mnp; sm[5][tid] = mxp;
  __syncthreads();
  for (int st = 128; st > 0; st >>= 1) {
    if (tid < st) {
      sm[0][tid] = min(sm[0][tid], sm[0][tid + st]);
      sm[1][tid] = max(sm[1][tid], sm[1][tid + st]);
      sm[2][tid] = min(sm[2][tid], sm[2][tid + st]);
      sm[3][tid] = max(sm[3][tid], sm[3][tid + st]);
      sm[4][tid] = min(sm[4][tid], sm[4][tid + st]);
      sm[5][tid] = max(sm[5][tid], sm[5][tid + st]);
    }
    __syncthreads();
  }
  if (tid == 0) {
    atomicMin(&mm[6 * b + 0], sm[0][0]); atomicMax(&mm[6 * b + 1], sm[1][0]);
    atomicMin(&mm[6 * b + 2], sm[2][0]); atomicMax(&mm[6 * b + 3], sm[3][0]);
    atomicMin(&mm[6 * b + 4], sm[4][0]); atomicMax(&mm[6 * b + 5], sm[5][0]);
  }
}

// torch.histc-style bin: exact f32 op sequence of the reference
__device__ __forceinline__ int bin_of(float v, float vmin, float den) {
  float tt = __fsub_rn(v, vmin);
  float q = __fdiv_rn(tt, den);
  float z = __fmul_rn(q, 100.0f);
  z = fminf(fmaxf(z, 0.0f), 99.0f);
  return (int)z;  // trunc toward zero, matches astype(int32)
}

// ---- pass 2: histograms (exact integer counts)
__global__ void k_hist(const float* __restrict__ x, const u32* __restrict__ mm,
                       u32* __restrict__ hist) {
  __shared__ u32 h[300];
  for (int i = threadIdx.x; i < 300; i += 256) h[i] = 0u;
  __syncthreads();
  const long long blk_base = (long long)blockIdx.x * 4096;
  const int b = (int)(blk_base / 7340032LL);
  const int t = (int)((blk_base % 7340032LL) / FRAME);
  const long long base = ((long long)(b * TT + t)) * FRAME;
  const long long w0 = blk_base % FRAME;
  float mn_t = decf(mm[6 * b + 0]), den_t = __fsub_rn(decf(mm[6 * b + 1]), decf(mm[6 * b + 0]));
  float mn_1 = decf(mm[6 * b + 2]), den_1 = __fsub_rn(decf(mm[6 * b + 3]), decf(mm[6 * b + 2]));
  float mn_p = decf(mm[6 * b + 4]), den_p = __fsub_rn(decf(mm[6 * b + 5]), decf(mm[6 * b + 4]));
  for (int k = 0; k < 16; ++k) {
    long long w = w0 + threadIdx.x + (k << 8);
    float a = x[base + w];
    float c = x[base + FRAME + w];
    float p = __fmul_rn(a, c);
    atomicAdd(&h[bin_of(a, mn_t, den_t)], 1u);
    atomicAdd(&h[100 + bin_of(c, mn_1, den_1)], 1u);
    atomicAdd(&h[200 + bin_of(p, mn_p, den_p)], 1u);
  }
  __syncthreads();
  for (int i = threadIdx.x; i < 300; i += 256) atomicAdd(&hist[b * 300 + i], h[i]);
}

// Eigen/XLA fast-tanh rational interpolant (f32), the exact poly XLA CPU emits
__device__ float tanh_emul(float a) {
  const float kClamp = 7.90531110763549805f;
  float xx = fminf(fmaxf(a, -kClamp), kClamp);
  float x2 = __fmul_rn(xx, xx);
#if TANH_FMA
  float p = __fmaf_rn(x2, -2.76076847742355e-16f, 2.00018790482477e-13f);
  p = __fmaf_rn(x2, p, -8.60467152213735e-11f);
  p = __fmaf_rn(x2, p, 5.12229709037114e-08f);
  p = __fmaf_rn(x2, p, 1.48572235717979e-05f);
  p = __fmaf_rn(x2, p, 6.37261928875436e-04f);
  p = __fmaf_rn(x2, p, 4.89352455891786e-03f);
  p = __fmul_rn(xx, p);
  float q = __fmaf_rn(x2, 1.19825839466702e-06f, 1.18534705686654e-04f);
  q = __fmaf_rn(x2, q, 2.26843463243900e-03f);
  q = __fmaf_rn(x2, q, 4.89352518554385e-03f);
#else
  float p = __fadd_rn(__fmul_rn(x2, -2.76076847742355e-16f), 2.00018790482477e-13f);
  p = __fadd_rn(__fmul_rn(x2, p), -8.60467152213735e-11f);
  p = __fadd_rn(__fmul_rn(x2, p), 5.12229709037114e-08f);
  p = __fadd_rn(__fmul_rn(x2, p), 1.48572235717979e-05f);
  p = __fadd_rn(__fmul_rn(x2, p), 6.37261928875436e-04f);
  p = __fadd_rn(__fmul_rn(x2, p), 4.89352455891786e-03f);
  p = __fmul_rn(xx, p);
  float q = __fadd_rn(__fmul_rn(x2, 1.19825839466702e-06f), 1.18534705686654e-04f);
  q = __fadd_rn(__fmul_rn(x2, q), 2.26843463243900e-03f);
  q = __fadd_rn(__fmul_rn(x2, q), 4.89352518554385e-03f);
#endif
  float r = __fdiv_rn(p, q);
  if (fabsf(a) < 0.0004f) r = a;
  return r;
}

// ---- mi + corr per batch; strictly serial f32 emulation (one thread per batch)
__global__ void k_corr(const u32* __restrict__ hist, float* __restrict__ corr) {
  int b = threadIdx.x;
  if (b >= 4) return;
  const u32* HX = hist + b * 300;
  const u32* HX1 = HX + 100;
  const u32* HJ = HX + 200;
  float Sj = 0.0f;
  for (int i = 0; i < 100; ++i) Sj = __fadd_rn(Sj, (float)HJ[i]);  // exact 7340032.0
  float hx[100], hx1[100];
  float Sx = 0.0f, Sx1 = 0.0f;
  for (int i = 0; i < 100; ++i) { hx[i] = __fdiv_rn((float)HX[i], NELF); Sx = __fadd_rn(Sx, hx[i]); }
  for (int i = 0; i < 100; ++i) { hx1[i] = __fdiv_rn((float)HX1[i], NELF); Sx1 = __fadd_rn(Sx1, hx1[i]); }
  float mi = 0.0f;
  for (int i = 0; i < 100; ++i) {
    float pj = __fdiv_rn((float)HJ[i], Sj);
    float px = __fdiv_rn(hx[i], Sx);
    float px1 = __fdiv_rn(hx1[i], Sx1);
    // correctly-rounded f32 log via double (matches glibc logf to ~0.5ulp)
    float la = (float)log((double)__fadd_rn(pj, 1e-10f));
    float lb = (float)log((double)__fadd_rn(__fmul_rn(px, px1), 1e-10f));
    float term = __fmul_rn(pj, __fsub_rn(la, lb));
    mi = __fadd_rn(mi, term);
  }
  float lm = (float)log((double)mi);
  float th = tanh_emul(lm);
  float num = (float)exp(0.8);  // np.e ** 0.8, weak-cast to f32 by jax
  corr[b] = __fdiv_rn(num, th);
}

// ---- mag[b,f,s] = sequential f32 sum over c of fl(fl(x1-x0)+corr[b])
__global__ void k_mag(const float* __restrict__ x, const float* __restrict__ corr,
                      float* __restrict__ mag) {
  int gid = blockIdx.x * 256 + threadIdx.x;   // 0..28*65536-1
  int bf = gid >> 16;
  int s = gid & 65535;
  int b = bf / NF, f = bf % NF;
  int g = s >> 6, i = (s >> 3) & 7, j = s & 7;
  int gy = g >> 5, gx = g & 31;
  int hw = (gy * 8 + i) * 256 + gx * 8 + j;
  const float cb = corr[b];
  long long base = ((long long)(b * TT + f)) * FRAME + hw;
  float acc = 0.0f;
  for (int c = 0; c < CC; ++c) {
    float a0 = x[base + (long long)c * HWN];
    float a1 = x[base + FRAME + (long long)c * HWN];
    acc = __fadd_rn(acc, __fadd_rn(__fsub_rn(a1, a0), cb));
  }
  mag[gid] = acc;
}

// ---- stable top-64 (value desc, index asc) per (b,f). mag is NaN-free.
__global__ void __launch_bounds__(1024) k_top64(const float* __restrict__ mag,
                                                int* __restrict__ top) {
  int bf = blockIdx.x;
  const float* m = mag + (long long)bf * SEG;
  __shared__ u32 bitmap[2048];
  __shared__ u64 red[1024];
  int tid = threadIdx.x;
  for (int i = tid; i < 2048; i += 1024) bitmap[i] = 0u;
  __syncthreads();
  for (int round = 0; round < 64; ++round) {
    u64 best = 0ull;
    for (int k = 0; k < 64; ++k) {
      int s = tid + (k << 10);
      if (bitmap[s >> 5] & (1u << (s & 31))) continue;
      u64 cand = ((u64)encf(m[s]) << 32) | (u64)(0xFFFFFFFFu - (u32)s);
      best = max(best, cand);
    }
    red[tid] = best;
    __syncthreads();
    for (int st = 512; st > 0; st >>= 1) {
      if (tid < st) red[tid] = max(red[tid], red[tid + st]);
      __syncthreads();
    }
    if (tid == 0) {
      int s = (int)(0xFFFFFFFFu - (u32)(red[0] & 0xFFFFFFFFull));
      top[bf * 64 + round] = s;
      bitmap[s >> 5] |= (1u << (s & 31));
    }
    __syncthreads();
  }
}

// ---- centers -> cov -> inv -> maha -> stable top-169 -> graph
__global__ void __launch_bounds__(256) k_graph(const int* __restrict__ top,
                                               float* __restrict__ out) {
  int bf = blockIdx.x;
  int tid = threadIdx.x;
  __shared__ float cy[64], cx[64];
  __shared__ float inv[4];
  __shared__ u32 keys[4096];
  __shared__ u64 red[256];
  if (tid < 64) {
    int idx = top[bf * 64 + tid];
    cy[tid] = (float)((idx >> 6) * 8 + 4);   // divisor is NUM_REGIONS=64, per reference
    cx[tid] = (float)((idx & 63) * 8 + 4);
  }
  __syncthreads();
  if (tid == 0) {
    // mean (exact), d (exact), cov: sequential f32 like XLA's reduce/dot
    float sy = 0.f, sx = 0.f;
    for (int r = 0; r < 64; ++r) sy = __fadd_rn(sy, cy[r]);
    for (int r = 0; r < 64; ++r) sx = __fadd_rn(sx, cx[r]);
    float my = __fdiv_rn(sy, 64.0f), mx = __fdiv_rn(sx, 64.0f);
    float c00 = 0.f, c01 = 0.f, c11 = 0.f;
    for (int r = 0; r < 64; ++r) {
      float dy = __fsub_rn(cy[r], my);
      float dx = __fsub_rn(cx[r], mx);
      c00 = __fadd_rn(c00, __fmul_rn(dy, dy));
      c01 = __fadd_rn(c01, __fmul_rn(dy, dx));
      c11 = __fadd_rn(c11, __fmul_rn(dx, dx));
    }
    c00 = __fdiv_rn(c00, 63.0f); c01 = __fdiv_rn(c01, 63.0f); c11 = __fdiv_rn(c11, 63.0f);
    c00 = __fadd_rn(c00, 1e-6f); c11 = __fadd_rn(c11, 1e-6f);
    // inv: f64 adjugate rounded to f32 (~1ulp of ref's f32 LU; output is
    // set-valued in top-169 so crumb-level diffs are safe)
    double det = (double)c00 * (double)c11 - (double)c01 * (double)c01;
    inv[0] = (float)((double)c11 / det);
    inv[1] = (float)(-(double)c01 / det);
    inv[2] = inv[1];
    inv[3] = (float)((double)c00 / det);
  }
  __syncthreads();
  float i00 = inv[0], i01 = inv[1], i10 = inv[2], i11 = inv[3];
  long long obase = (long long)bf * 4096;
  for (int e = tid; e < 4096; e += 256) {
    int q = e >> 6, r = e & 63;
    float d0 = __fsub_rn(cy[r], cy[q]);   // diff[q,r] = c_r - c_q
    float d1 = __fsub_rn(cx[r], cx[q]);
    // v_d = fl(fl(0+d0*inv[0][d]) + d1*inv[1][d])  (reduce-with-0-init semantics)
    float v0 = __fadd_rn(__fadd_rn(0.0f, __fmul_rn(d0, i00)), __fmul_rn(d1, i10));
    float v1 = __fadd_rn(__fadd_rn(0.0f, __fmul_rn(d0, i01)), __fmul_rn(d1, i11));
    float p0 = __fmul_rn(v0, d0);
    float p1 = __fmul_rn(v1, d1);
    float s0 = __fsqrt_rn(p0);            // NaN when p0 < 0 — this HAPPENS
    float s1 = __fsqrt_rn(p1);
    float mh = __fadd_rn(__fadd_rn(0.0f, s0), s1);
    u32 key;
    if (mh != mh) {
#if NAN_POLICY_A
      key = 0xFFFFFFFFu;   // -(-NaN) = +NaN: totalorder sorts above +inf -> selected first
#else
      key = 0u;            // placeholder for POLICY C (libstdc++ heap emulation)
#endif
    } else {
      key = encf(-mh);     // descending sort key on -maha, total order (handles -0 vs +0)
    }
    keys[e] = key;
    out[obase + e] = 0.0f;
  }
  __syncthreads();
  for (int round = 0; round < 169; ++round) {
    u64 best = 0ull;
    for (int k = 0; k < 16; ++k) {
      int e = tid + (k << 8);
      u32 ky = keys[e];
      if (ky == 0u) continue;  // selected sentinel (no finite key maps to 0)
      u64 cand = ((u64)ky << 32) | (u64)(0xFFFFFFFFu - (u32)e);
      best = max(best, cand);
    }
    red[tid] = best;
    __syncthreads();
    for (int st = 128; st > 0; st >>= 1) {
      if (tid < st) red[tid] = max(red[tid], red[tid + st]);
      __syncthreads();
    }
    if (tid == 0) {
      int e = (int)(0xFFFFFFFFu - (u32)(red[0] & 0xFFFFFFFFull));
      out[obase + e] = 1.0f;
      keys[e] = 0u;
    }
    __syncthreads();
  }
}

extern "C" void kernel_launch(void* const* d_in, const int* in_sizes, int n_in,
                              void* d_out, int out_size, void* d_ws, size_t ws_size,
                              hipStream_t stream) {
  if (ws_size < (size_t)WS_NEED) return;  // need ~7.4 MB scratch
  const float* x = (const float*)d_in[0];
  float* out = (float*)d_out;
  char* ws = (char*)d_ws;
  u32* mm = (u32*)(ws + WS_MM);
  float* corr = (float*)(ws + WS_CORR);
  u32* hist = (u32*)(ws + WS_HIST);
  int* top = (int*)(ws + WS_TOP);
  float* mag = (float*)(ws + WS_MAG);

  hipLaunchKernelGGL(k_init, dim3(1), dim3(256), 0, stream, (u32*)ws);
  hipLaunchKernelGGL(k_minmax, dim3(7168), dim3(256), 0, stream, x, mm);
  hipLaunchKernelGGL(k_hist, dim3(7168), dim3(256), 0, stream, x, mm, hist);
  hipLaunchKernelGGL(k_corr, dim3(1), dim3(64), 0, stream, hist, corr);
  hipLaunchKernelGGL(k_mag, dim3(7168), dim3(256), 0, stream, x, corr, mag);
  hipLaunchKernelGGL(k_top64, dim3(28), dim3(1024), 0, stream, mag, top);
  hipLaunchKernelGGL(k_graph, dim3(28), dim3(256), 0, stream, top, out);
}

// Round 2
// 796.311 us; speedup vs baseline: 2.0997x; 2.0997x over previous
//
#include <hip/hip_runtime.h>
#include <stdint.h>

// ============================================================================
// Motion_Relation_Mining — bit-exact replication of the JAX (CPU) reference.
//
// FROZEN (verified passing in R0, absmax 0.0): all f32 op sequences,
// NAN_POLICY_A (NaN maha sorts first in top-169), FMA-tanh, sequential
// reduce orders, packed (value desc, index asc) selection semantics.
//
// R1: replaced the two iterative arg-max selection kernels (64 and 169
// serial rounds) with MSB-first radix-select — mathematically identical
// selection set + order, ~100x less serial work.
// ============================================================================

typedef unsigned int u32;
typedef unsigned long long u64;

// sizes
#define BB 4
#define TT 8
#define CC 16
#define HWN 65536              // H*W = 256*256
#define NF 7
#define FRAME 1048576LL        // C*H*W
#define NELF 7340032.0f        // nf*C*H*W per batch (exact in f32)
#define NPAIR 28               // B*nf
#define SEG 65536              // G*rs*rs spatial positions

// ws layout (bytes)
#define WS_MM 0                // u32[4][6]
#define WS_CORR 128            // float[4]
#define WS_HIST 512            // u32[4][3][100]
#define WS_TOP 8192            // int[28][64]
#define WS_MAG 16384           // float[28][65536]
#define WS_NEED (16384 + 28LL*65536*4)

__device__ __forceinline__ u32 encf(float f) {
  u32 u = __float_as_uint(f);
  return (u & 0x80000000u) ? ~u : (u | 0x80000000u);
}
__device__ __forceinline__ float decf(u32 e) {
  u32 u = (e & 0x80000000u) ? (e ^ 0x80000000u) : ~e;
  return __uint_as_float(u);
}

__global__ void k_init(u32* ws) {
  int t = threadIdx.x;
  if (t < 24) ws[t] = ((t & 1) == 0) ? 0xFFFFFFFFu : 0u;
  for (int i = t; i < 1200; i += 256) ws[(WS_HIST / 4) + i] = 0u;
}

// ---- pass 1: per-batch min/max of x_t, x_t1, x_t*x_t1 (exact; encoded u32)
__global__ void k_minmax(const float* __restrict__ x, u32* __restrict__ mm) {
  const long long blk_base = (long long)blockIdx.x * 4096;
  const int b = (int)(blk_base / 7340032LL);
  const int t = (int)((blk_base % 7340032LL) / FRAME);
  const long long base = ((long long)(b * TT + t)) * FRAME;
  const long long w0 = blk_base % FRAME;
  u32 mn0 = 0xFFFFFFFFu, mx0 = 0u, mn1 = 0xFFFFFFFFu, mx1 = 0u, mnp = 0xFFFFFFFFu, mxp = 0u;
  for (int k = 0; k < 16; ++k) {
    long long w = w0 + threadIdx.x + (k << 8);
    float a = x[base + w];
    float c = x[base + FRAME + w];
    float p = __fmul_rn(a, c);
    u32 ea = encf(a), ec = encf(c), ep = encf(p);
    mn0 = min(mn0, ea); mx0 = max(mx0, ea);
    mn1 = min(mn1, ec); mx1 = max(mx1, ec);
    mnp = min(mnp, ep); mxp = max(mxp, ep);
  }
  __shared__ u32 sm[6][256];
  int tid = threadIdx.x;
  sm[0][tid] = mn0; sm[1][tid] = mx0; sm[2][tid] = mn1;
  sm[3][tid] = mx1; sm[4][tid] = mnp; sm[5][tid] = mxp;
  __syncthreads();
  for (int st = 128; st > 0; st >>= 1) {
    if (tid < st) {
      sm[0][tid] = min(sm[0][tid], sm[0][tid + st]);
      sm[1][tid] = max(sm[1][tid], sm[1][tid + st]);
      sm[2][tid] = min(sm[2][tid], sm[2][tid + st]);
      sm[3][tid] = max(sm[3][tid], sm[3][tid + st]);
      sm[4][tid] = min(sm[4][tid], sm[4][tid + st]);
      sm[5][tid] = max(sm[5][tid], sm[5][tid + st]);
    }
    __syncthreads();
  }
  if (tid == 0) {
    atomicMin(&mm[6 * b + 0], sm[0][0]); atomicMax(&mm[6 * b + 1], sm[1][0]);
    atomicMin(&mm[6 * b + 2], sm[2][0]); atomicMax(&mm[6 * b + 3], sm[3][0]);
    atomicMin(&mm[6 * b + 4], sm[4][0]); atomicMax(&mm[6 * b + 5], sm[5][0]);
  }
}

__device__ __forceinline__ int bin_of(float v, float vmin, float den) {
  float tt = __fsub_rn(v, vmin);
  float q = __fdiv_rn(tt, den);
  float z = __fmul_rn(q, 100.0f);
  z = fminf(fmaxf(z, 0.0f), 99.0f);
  return (int)z;
}

// ---- pass 2: histograms (exact integer counts)
__global__ void k_hist(const float* __restrict__ x, const u32* __restrict__ mm,
                       u32* __restrict__ hist) {
  __shared__ u32 h[300];
  for (int i = threadIdx.x; i < 300; i += 256) h[i] = 0u;
  __syncthreads();
  const long long blk_base = (long long)blockIdx.x * 4096;
  const int b = (int)(blk_base / 7340032LL);
  const int t = (int)((blk_base % 7340032LL) / FRAME);
  const long long base = ((long long)(b * TT + t)) * FRAME;
  const long long w0 = blk_base % FRAME;
  float mn_t = decf(mm[6 * b + 0]), den_t = __fsub_rn(decf(mm[6 * b + 1]), decf(mm[6 * b + 0]));
  float mn_1 = decf(mm[6 * b + 2]), den_1 = __fsub_rn(decf(mm[6 * b + 3]), decf(mm[6 * b + 2]));
  float mn_p = decf(mm[6 * b + 4]), den_p = __fsub_rn(decf(mm[6 * b + 5]), decf(mm[6 * b + 4]));
  for (int k = 0; k < 16; ++k) {
    long long w = w0 + threadIdx.x + (k << 8);
    float a = x[base + w];
    float c = x[base + FRAME + w];
    float p = __fmul_rn(a, c);
    atomicAdd(&h[bin_of(a, mn_t, den_t)], 1u);
    atomicAdd(&h[100 + bin_of(c, mn_1, den_1)], 1u);
    atomicAdd(&h[200 + bin_of(p, mn_p, den_p)], 1u);
  }
  __syncthreads();
  for (int i = threadIdx.x; i < 300; i += 256) atomicAdd(&hist[b * 300 + i], h[i]);
}

// Eigen/XLA fast-tanh rational interpolant (FMA form) — FROZEN
__device__ float tanh_emul(float a) {
  const float kClamp = 7.90531110763549805f;
  float xx = fminf(fmaxf(a, -kClamp), kClamp);
  float x2 = __fmul_rn(xx, xx);
  float p = __fmaf_rn(x2, -2.76076847742355e-16f, 2.00018790482477e-13f);
  p = __fmaf_rn(x2, p, -8.60467152213735e-11f);
  p = __fmaf_rn(x2, p, 5.12229709037114e-08f);
  p = __fmaf_rn(x2, p, 1.48572235717979e-05f);
  p = __fmaf_rn(x2, p, 6.37261928875436e-04f);
  p = __fmaf_rn(x2, p, 4.89352455891786e-03f);
  p = __fmul_rn(xx, p);
  float q = __fmaf_rn(x2, 1.19825839466702e-06f, 1.18534705686654e-04f);
  q = __fmaf_rn(x2, q, 2.26843463243900e-03f);
  q = __fmaf_rn(x2, q, 4.89352518554385e-03f);
  float r = __fdiv_rn(p, q);
  if (fabsf(a) < 0.0004f) r = a;
  return r;
}

// ---- mi + corr per batch; strictly serial f32 emulation — FROZEN
__global__ void k_corr(const u32* __restrict__ hist, float* __restrict__ corr) {
  int b = threadIdx.x;
  if (b >= 4) return;
  const u32* HX = hist + b * 300;
  const u32* HX1 = HX + 100;
  const u32* HJ = HX + 200;
  float Sj = 0.0f;
  for (int i = 0; i < 100; ++i) Sj = __fadd_rn(Sj, (float)HJ[i]);
  float hx[100], hx1[100];
  float Sx = 0.0f, Sx1 = 0.0f;
  for (int i = 0; i < 100; ++i) { hx[i] = __fdiv_rn((float)HX[i], NELF); Sx = __fadd_rn(Sx, hx[i]); }
  for (int i = 0; i < 100; ++i) { hx1[i] = __fdiv_rn((float)HX1[i], NELF); Sx1 = __fadd_rn(Sx1, hx1[i]); }
  float mi = 0.0f;
  for (int i = 0; i < 100; ++i) {
    float pj = __fdiv_rn((float)HJ[i], Sj);
    float px = __fdiv_rn(hx[i], Sx);
    float px1 = __fdiv_rn(hx1[i], Sx1);
    float la = (float)log((double)__fadd_rn(pj, 1e-10f));
    float lb = (float)log((double)__fadd_rn(__fmul_rn(px, px1), 1e-10f));
    float term = __fmul_rn(pj, __fsub_rn(la, lb));
    mi = __fadd_rn(mi, term);
  }
  float lm = (float)log((double)mi);
  float th = tanh_emul(lm);
  float num = (float)exp(0.8);
  corr[b] = __fdiv_rn(num, th);
}

// ---- mag[b,f,s] = sequential f32 sum over c of fl(fl(x1-x0)+corr[b]) — FROZEN
__global__ void k_mag(const float* __restrict__ x, const float* __restrict__ corr,
                      float* __restrict__ mag) {
  int gid = blockIdx.x * 256 + threadIdx.x;
  int bf = gid >> 16;
  int s = gid & 65535;
  int b = bf / NF, f = bf % NF;
  int g = s >> 6, i = (s >> 3) & 7, j = s & 7;
  int gy = g >> 5, gx = g & 31;
  int hw = (gy * 8 + i) * 256 + gx * 8 + j;
  const float cb = corr[b];
  long long base = ((long long)(b * TT + f)) * FRAME + hw;
  float acc = 0.0f;
  for (int c = 0; c < CC; ++c) {
    float a0 = x[base + (long long)c * HWN];
    float a1 = x[base + FRAME + (long long)c * HWN];
    acc = __fadd_rn(acc, __fadd_rn(__fsub_rn(a1, a0), cb));
  }
  mag[gid] = acc;
}

// ---- top-64 per (b,f): MSB-first radix-select, identical to stable
// (value desc, index asc) iterative selection. Values register-resident.
__global__ void __launch_bounds__(1024) k_top64(const float* __restrict__ mag,
                                                int* __restrict__ top) {
  int bf = blockIdx.x;
  const float* m = mag + (long long)bf * SEG;
  int tid = threadIdx.x;
  __shared__ u32 bins[256];
  __shared__ u64 sel[64];
  __shared__ u32 tie[2048];
  __shared__ u32 scal[4];     // 0: prefix, 1: need, 2: selcnt, 3: tiecnt

  u32 enc[64];
#pragma unroll
  for (int k = 0; k < 64; ++k) enc[k] = encf(m[tid + (k << 10)]);

  u32 prefix = 0u, need = 64u;
  for (int pass = 0; pass < 4; ++pass) {
    int shift = 24 - pass * 8;
    if (tid < 256) bins[tid] = 0u;
    __syncthreads();
#pragma unroll
    for (int k = 0; k < 64; ++k) {
      u32 e = enc[k];
      bool ok = (pass == 0) || ((e >> (shift + 8)) == (prefix >> (shift + 8)));
      if (ok) atomicAdd(&bins[(e >> shift) & 0xFFu], 1u);
    }
    __syncthreads();
    if (tid == 0) {
      u32 cum = 0; int d = 255;
      for (; d >= 0; --d) {
        u32 c = bins[d];
        if (cum + c >= need) break;
        cum += c;
      }
      if (d < 0) d = 0;  // unreachable (group count >= need by invariant)
      scal[0] = prefix | ((u32)d << shift);
      scal[1] = need - cum;
      scal[2] = 0u; scal[3] = 0u;
    }
    __syncthreads();
    prefix = scal[0]; need = scal[1];
    __syncthreads();
  }

  // collect: enc > K* definitely in; enc == K* -> tie group (pick smallest idx)
#pragma unroll
  for (int k = 0; k < 64; ++k) {
    u32 e = enc[k];
    int s = tid + (k << 10);
    if (e > prefix) {
      u32 p = atomicAdd(&scal[2], 1u);
      sel[p] = ((u64)e << 32) | (u64)(0xFFFFFFFFu - (u32)s);
    } else if (e == prefix) {
      u32 p = atomicAdd(&scal[3], 1u);
      if (p < 2048u) tie[p] = (u32)s;
    }
  }
  __syncthreads();
  int tc = (int)scal[3];
  int k2 = (int)need;
  for (int i = tid; i < tc; i += 1024) {
    u32 si = tie[i];
    int rank = 0;
    for (int j = 0; j < tc; ++j) rank += (tie[j] < si);
    if (rank < k2) {
      u32 p = atomicAdd(&scal[2], 1u);
      sel[p] = ((u64)prefix << 32) | (u64)(0xFFFFFFFFu - si);
    }
  }
  __syncthreads();

  // emit in rank order (keys unique): rank r = #(keys greater)
  if (tid < 64) {
    u64 mine = sel[tid];
    int rank = 0;
    for (int j = 0; j < 64; ++j) rank += (sel[j] > mine);
    int s = (int)(0xFFFFFFFFu - (u32)(mine & 0xFFFFFFFFull));
    top[bf * 64 + rank] = s;
  }
}

// ---- centers -> cov -> inv -> maha -> radix-select top-169 (set) -> graph
__global__ void __launch_bounds__(256) k_graph(const int* __restrict__ top,
                                               float* __restrict__ out) {
  int bf = blockIdx.x;
  int tid = threadIdx.x;
  __shared__ float cy[64], cx[64];
  __shared__ float inv[4];
  __shared__ u32 keys[4096];
  __shared__ u32 bins[256];
  __shared__ u32 tie[4096];
  __shared__ u32 scal[4];
  if (tid < 64) {
    int idx = top[bf * 64 + tid];
    cy[tid] = (float)((idx >> 6) * 8 + 4);
    cx[tid] = (float)((idx & 63) * 8 + 4);
  }
  __syncthreads();
  if (tid == 0) {
    float sy = 0.f, sx = 0.f;
    for (int r = 0; r < 64; ++r) sy = __fadd_rn(sy, cy[r]);
    for (int r = 0; r < 64; ++r) sx = __fadd_rn(sx, cx[r]);
    float my = __fdiv_rn(sy, 64.0f), mx = __fdiv_rn(sx, 64.0f);
    float c00 = 0.f, c01 = 0.f, c11 = 0.f;
    for (int r = 0; r < 64; ++r) {
      float dy = __fsub_rn(cy[r], my);
      float dx = __fsub_rn(cx[r], mx);
      c00 = __fadd_rn(c00, __fmul_rn(dy, dy));
      c01 = __fadd_rn(c01, __fmul_rn(dy, dx));
      c11 = __fadd_rn(c11, __fmul_rn(dx, dx));
    }
    c00 = __fdiv_rn(c00, 63.0f); c01 = __fdiv_rn(c01, 63.0f); c11 = __fdiv_rn(c11, 63.0f);
    c00 = __fadd_rn(c00, 1e-6f); c11 = __fadd_rn(c11, 1e-6f);
    double det = (double)c00 * (double)c11 - (double)c01 * (double)c01;
    inv[0] = (float)((double)c11 / det);
    inv[1] = (float)(-(double)c01 / det);
    inv[2] = inv[1];
    inv[3] = (float)((double)c00 / det);
  }
  __syncthreads();
  float i00 = inv[0], i01 = inv[1], i10 = inv[2], i11 = inv[3];
  long long obase = (long long)bf * 4096;
  for (int e = tid; e < 4096; e += 256) {
    int q = e >> 6, r = e & 63;
    float d0 = __fsub_rn(cy[r], cy[q]);
    float d1 = __fsub_rn(cx[r], cx[q]);
    float v0 = __fadd_rn(__fadd_rn(0.0f, __fmul_rn(d0, i00)), __fmul_rn(d1, i10));
    float v1 = __fadd_rn(__fadd_rn(0.0f, __fmul_rn(d0, i01)), __fmul_rn(d1, i11));
    float p0 = __fmul_rn(v0, d0);
    float p1 = __fmul_rn(v1, d1);
    float s0 = __fsqrt_rn(p0);
    float s1 = __fsqrt_rn(p1);
    float mh = __fadd_rn(__fadd_rn(0.0f, s0), s1);
    u32 key;
    if (mh != mh) key = 0xFFFFFFFFu;   // NaN first (POLICY A, verified R0)
    else key = encf(-mh);              // smallest maha first, total order
    keys[e] = key;
    out[obase + e] = 0.0f;
  }
  __syncthreads();

  u32 prefix = 0u, need = 169u;
  for (int pass = 0; pass < 4; ++pass) {
    int shift = 24 - pass * 8;
    if (tid == 0) { scal[2] = 0u; }
    bins[tid] = 0u;
    __syncthreads();
    for (int k = 0; k < 16; ++k) {
      u32 ky = keys[tid + (k << 8)];
      bool ok = (pass == 0) || ((ky >> (shift + 8)) == (prefix >> (shift + 8)));
      if (ok) atomicAdd(&bins[(ky >> shift) & 0xFFu], 1u);
    }
    __syncthreads();
    if (tid == 0) {
      u32 cum = 0; int d = 255;
      for (; d >= 0; --d) {
        u32 c = bins[d];
        if (cum + c >= need) break;
        cum += c;
      }
      if (d < 0) d = 0;
      scal[0] = prefix | ((u32)d << shift);
      scal[1] = need - cum;
    }
    __syncthreads();
    prefix = scal[0]; need = scal[1];
    __syncthreads();
  }

  for (int k = 0; k < 16; ++k) {
    int e = tid + (k << 8);
    u32 ky = keys[e];
    if (ky > prefix) out[obase + e] = 1.0f;
    else if (ky == prefix) {
      u32 p = atomicAdd(&scal[2], 1u);
      tie[p] = (u32)e;
    }
  }
  __syncthreads();
  int tc = (int)scal[2];
  for (int i = tid; i < tc; i += 256) {
    u32 ei = tie[i];
    int rank = 0;
    for (int j = 0; j < tc; ++j) rank += (tie[j] < ei);
    if (rank < (int)need) out[obase + ei] = 1.0f;
  }
}

extern "C" void kernel_launch(void* const* d_in, const int* in_sizes, int n_in,
                              void* d_out, int out_size, void* d_ws, size_t ws_size,
                              hipStream_t stream) {
  if (ws_size < (size_t)WS_NEED) return;
  const float* x = (const float*)d_in[0];
  float* out = (float*)d_out;
  char* ws = (char*)d_ws;
  u32* mm = (u32*)(ws + WS_MM);
  float* corr = (float*)(ws + WS_CORR);
  u32* hist = (u32*)(ws + WS_HIST);
  int* top = (int*)(ws + WS_TOP);
  float* mag = (float*)(ws + WS_MAG);

  hipLaunchKernelGGL(k_init, dim3(1), dim3(256), 0, stream, (u32*)ws);
  hipLaunchKernelGGL(k_minmax, dim3(7168), dim3(256), 0, stream, x, mm);
  hipLaunchKernelGGL(k_hist, dim3(7168), dim3(256), 0, stream, x, mm, hist);
  hipLaunchKernelGGL(k_corr, dim3(1), dim3(64), 0, stream, hist, corr);
  hipLaunchKernelGGL(k_mag, dim3(7168), dim3(256), 0, stream, x, corr, mag);
  hipLaunchKernelGGL(k_top64, dim3(28), dim3(1024), 0, stream, mag, top);
  hipLaunchKernelGGL(k_graph, dim3(28), dim3(256), 0, stream, top, out);
}

// Round 3
// 394.463 us; speedup vs baseline: 4.2386x; 2.0187x over previous
//
#include <hip/hip_runtime.h>
#include <stdint.h>

// ============================================================================
// Motion_Relation_Mining — bit-exact replication of the JAX (CPU) reference.
//
// FROZEN (verified passing R0/R1, absmax 0.0): all f32 op sequences,
// NAN_POLICY_A, FMA-tanh, sequential reduce orders, radix-select semantics.
//
// R2: removed contended global atomics (Guideline 12):
//   - k_minmax -> single-pass-over-frames + per-block partials + reduce kernel
//     (min/max over per-frame values == min/max over pair views, exactly)
//   - k_hist   -> single-pass + 64 sub-histogram copies/batch + reduce kernel
//   Partial buffers overlaid on the mag region (consumed before k_mag writes),
//   so WS_NEED is unchanged from the proven R0 footprint.
// ============================================================================

typedef unsigned int u32;
typedef unsigned long long u64;

// sizes
#define BB 4
#define TT 8
#define CC 16
#define HWN 65536              // H*W
#define NF 7
#define FRAME 1048576LL        // C*H*W
#define NELF 7340032.0f        // nf*C*H*W per batch (exact in f32)
#define NPAIR 28
#define SEG 65536

// ws layout (bytes)
#define WS_MM 0                // u32[24] final min/max (encoded)
#define WS_CORR 128            // float[4]
#define WS_HIST 512            // u32[4][300] final histograms
#define WS_TOP 8192            // int[28][64]
#define WS_MAG 16384           // float[28][65536]
// overlaid inside WS_MAG region — fully consumed before k_mag writes:
#define WS_MMPART (WS_MAG)            // u32[2048][6]  = 48 KiB
#define WS_HISTC  (WS_MAG + 65536)    // u32[4][64][300] = 300 KiB
#define WS_NEED (16384 + 28LL*65536*4)

__device__ __forceinline__ u32 encf(float f) {
  u32 u = __float_as_uint(f);
  return (u & 0x80000000u) ? ~u : (u | 0x80000000u);
}
__device__ __forceinline__ float decf(u32 e) {
  u32 u = (e & 0x80000000u) ? (e ^ 0x80000000u) : ~e;
  return __uint_as_float(u);
}

// zero the 64x4 histogram copies (required each call: graph replays)
__global__ void k_init(u32* histc) {
  int i = blockIdx.x * 256 + threadIdx.x;
  if (i < 76800) histc[i] = 0u;
}

// ---- single pass over frames: per-batch min/max of x_t, x_t1, x_t*x_t1.
// Per-block partials written NON-atomically; reduced by k_mm_reduce.
__global__ void k_minmax_pass(const float* __restrict__ x, u32* __restrict__ part) {
  const int blk = blockIdx.x;            // 2048 blocks: 512 per batch
  const int b = blk >> 9;
  const long long w0 = (long long)(blk & 511) * 2048;
  const int tid = threadIdx.x;
  u32 mn0 = 0xFFFFFFFFu, mx0 = 0u, mn1 = 0xFFFFFFFFu, mx1 = 0u,
      mnp = 0xFFFFFFFFu, mxp = 0u;
  float prev[8];
  for (int t = 0; t < 8; ++t) {
    const float* fp = x + ((long long)(b * TT + t)) * FRAME + w0 + tid;
#pragma unroll
    for (int k = 0; k < 8; ++k) {
      float v = fp[k << 8];
      u32 ev = encf(v);
      if (t < 7) { mn0 = min(mn0, ev); mx0 = max(mx0, ev); }   // x_t view
      if (t > 0) {                                             // x_t1 view + product
        mn1 = min(mn1, ev); mx1 = max(mx1, ev);
        u32 ep = encf(__fmul_rn(prev[k], v));  // same rounding as R0 (commutative)
        mnp = min(mnp, ep); mxp = max(mxp, ep);
      }
      prev[k] = v;
    }
  }
  __shared__ u32 sm[6][256];
  sm[0][tid] = mn0; sm[1][tid] = mx0; sm[2][tid] = mn1;
  sm[3][tid] = mx1; sm[4][tid] = mnp; sm[5][tid] = mxp;
  __syncthreads();
  for (int st = 128; st > 0; st >>= 1) {
    if (tid < st) {
      sm[0][tid] = min(sm[0][tid], sm[0][tid + st]);
      sm[1][tid] = max(sm[1][tid], sm[1][tid + st]);
      sm[2][tid] = min(sm[2][tid], sm[2][tid + st]);
      sm[3][tid] = max(sm[3][tid], sm[3][tid + st]);
      sm[4][tid] = min(sm[4][tid], sm[4][tid + st]);
      sm[5][tid] = max(sm[5][tid], sm[5][tid + st]);
    }
    __syncthreads();
  }
  if (tid == 0) {
    u32* o = part + blk * 6;
    o[0] = sm[0][0]; o[1] = sm[1][0]; o[2] = sm[2][0];
    o[3] = sm[3][0]; o[4] = sm[4][0]; o[5] = sm[5][0];
  }
}

// 4 blocks (one per batch): reduce 512 partials -> mm[b*6..]
__global__ void k_mm_reduce(const u32* __restrict__ part, u32* __restrict__ mm) {
  const int b = blockIdx.x;
  const int tid = threadIdx.x;
  const u32* p0 = part + (b * 512 + tid) * 6;
  const u32* p1 = p0 + 256 * 6;
  __shared__ u32 sm[6][256];
  sm[0][tid] = min(p0[0], p1[0]); sm[1][tid] = max(p0[1], p1[1]);
  sm[2][tid] = min(p0[2], p1[2]); sm[3][tid] = max(p0[3], p1[3]);
  sm[4][tid] = min(p0[4], p1[4]); sm[5][tid] = max(p0[5], p1[5]);
  __syncthreads();
  for (int st = 128; st > 0; st >>= 1) {
    if (tid < st) {
      sm[0][tid] = min(sm[0][tid], sm[0][tid + st]);
      sm[1][tid] = max(sm[1][tid], sm[1][tid + st]);
      sm[2][tid] = min(sm[2][tid], sm[2][tid + st]);
      sm[3][tid] = max(sm[3][tid], sm[3][tid + st]);
      sm[4][tid] = min(sm[4][tid], sm[4][tid + st]);
      sm[5][tid] = max(sm[5][tid], sm[5][tid + st]);
    }
    __syncthreads();
  }
  if (tid == 0)
    for (int i = 0; i < 6; ++i) mm[b * 6 + i] = sm[i][0];
}

__device__ __forceinline__ int bin_of(float v, float vmin, float den) {
  float tt = __fsub_rn(v, vmin);
  float q = __fdiv_rn(tt, den);
  float z = __fmul_rn(q, 100.0f);
  z = fminf(fmaxf(z, 0.0f), 99.0f);
  return (int)z;
}

// ---- single pass over frames: LDS hist -> one of 64 global copies per batch
__global__ void k_hist_pass(const float* __restrict__ x, const u32* __restrict__ mm,
                            u32* __restrict__ histc) {
  __shared__ u32 h[300];
  for (int i = threadIdx.x; i < 300; i += 256) h[i] = 0u;
  __syncthreads();
  const int blk = blockIdx.x;
  const int b = blk >> 9;
  const long long w0 = (long long)(blk & 511) * 2048;
  const int tid = threadIdx.x;
  float mn_t = decf(mm[6 * b + 0]), den_t = __fsub_rn(decf(mm[6 * b + 1]), decf(mm[6 * b + 0]));
  float mn_1 = decf(mm[6 * b + 2]), den_1 = __fsub_rn(decf(mm[6 * b + 3]), decf(mm[6 * b + 2]));
  float mn_p = decf(mm[6 * b + 4]), den_p = __fsub_rn(decf(mm[6 * b + 5]), decf(mm[6 * b + 4]));
  float prev[8];
  for (int t = 0; t < 8; ++t) {
    const float* fp = x + ((long long)(b * TT + t)) * FRAME + w0 + tid;
#pragma unroll
    for (int k = 0; k < 8; ++k) {
      float v = fp[k << 8];
      if (t < 7) atomicAdd(&h[bin_of(v, mn_t, den_t)], 1u);
      if (t > 0) {
        atomicAdd(&h[100 + bin_of(v, mn_1, den_1)], 1u);
        float p = __fmul_rn(prev[k], v);
        atomicAdd(&h[200 + bin_of(p, mn_p, den_p)], 1u);
      }
      prev[k] = v;
    }
  }
  __syncthreads();
  u32* dst = histc + ((b << 6) + (blk & 63)) * 300;  // 8 blocks per copy
  for (int i = threadIdx.x; i < 300; i += 256) atomicAdd(&dst[i], h[i]);
}

// 4 blocks x 320 threads: hist[b*300+i] = sum of 64 copies (exact integers)
__global__ void k_hist_reduce(const u32* __restrict__ histc, u32* __restrict__ hist) {
  int b = blockIdx.x, i = threadIdx.x;
  if (i < 300) {
    const u32* src = histc + (b << 6) * 300 + i;
    u32 s = 0;
    for (int c = 0; c < 64; ++c) s += src[c * 300];
    hist[b * 300 + i] = s;
  }
}

// Eigen/XLA fast-tanh rational interpolant (FMA form) — FROZEN
__device__ float tanh_emul(float a) {
  const float kClamp = 7.90531110763549805f;
  float xx = fminf(fmaxf(a, -kClamp), kClamp);
  float x2 = __fmul_rn(xx, xx);
  float p = __fmaf_rn(x2, -2.76076847742355e-16f, 2.00018790482477e-13f);
  p = __fmaf_rn(x2, p, -8.60467152213735e-11f);
  p = __fmaf_rn(x2, p, 5.12229709037114e-08f);
  p = __fmaf_rn(x2, p, 1.48572235717979e-05f);
  p = __fmaf_rn(x2, p, 6.37261928875436e-04f);
  p = __fmaf_rn(x2, p, 4.89352455891786e-03f);
  p = __fmul_rn(xx, p);
  float q = __fmaf_rn(x2, 1.19825839466702e-06f, 1.18534705686654e-04f);
  q = __fmaf_rn(x2, q, 2.26843463243900e-03f);
  q = __fmaf_rn(x2, q, 4.89352518554385e-03f);
  float r = __fdiv_rn(p, q);
  if (fabsf(a) < 0.0004f) r = a;
  return r;
}

// ---- mi + corr per batch; strictly serial f32 emulation — FROZEN
__global__ void k_corr(const u32* __restrict__ hist, float* __restrict__ corr) {
  int b = threadIdx.x;
  if (b >= 4) return;
  const u32* HX = hist + b * 300;
  const u32* HX1 = HX + 100;
  const u32* HJ = HX + 200;
  float Sj = 0.0f;
  for (int i = 0; i < 100; ++i) Sj = __fadd_rn(Sj, (float)HJ[i]);
  float hx[100], hx1[100];
  float Sx = 0.0f, Sx1 = 0.0f;
  for (int i = 0; i < 100; ++i) { hx[i] = __fdiv_rn((float)HX[i], NELF); Sx = __fadd_rn(Sx, hx[i]); }
  for (int i = 0; i < 100; ++i) { hx1[i] = __fdiv_rn((float)HX1[i], NELF); Sx1 = __fadd_rn(Sx1, hx1[i]); }
  float mi = 0.0f;
  for (int i = 0; i < 100; ++i) {
    float pj = __fdiv_rn((float)HJ[i], Sj);
    float px = __fdiv_rn(hx[i], Sx);
    float px1 = __fdiv_rn(hx1[i], Sx1);
    float la = (float)log((double)__fadd_rn(pj, 1e-10f));
    float lb = (float)log((double)__fadd_rn(__fmul_rn(px, px1), 1e-10f));
    float term = __fmul_rn(pj, __fsub_rn(la, lb));
    mi = __fadd_rn(mi, term);
  }
  float lm = (float)log((double)mi);
  float th = tanh_emul(lm);
  float num = (float)exp(0.8);
  corr[b] = __fdiv_rn(num, th);
}

// ---- mag[b,f,s] = sequential f32 sum over c of fl(fl(x1-x0)+corr[b]) — FROZEN
__global__ void k_mag(const float* __restrict__ x, const float* __restrict__ corr,
                      float* __restrict__ mag) {
  int gid = blockIdx.x * 256 + threadIdx.x;
  int bf = gid >> 16;
  int s = gid & 65535;
  int b = bf / NF, f = bf % NF;
  int g = s >> 6, i = (s >> 3) & 7, j = s & 7;
  int gy = g >> 5, gx = g & 31;
  int hw = (gy * 8 + i) * 256 + gx * 8 + j;
  const float cb = corr[b];
  long long base = ((long long)(b * TT + f)) * FRAME + hw;
  float acc = 0.0f;
  for (int c = 0; c < CC; ++c) {
    float a0 = x[base + (long long)c * HWN];
    float a1 = x[base + FRAME + (long long)c * HWN];
    acc = __fadd_rn(acc, __fadd_rn(__fsub_rn(a1, a0), cb));
  }
  mag[gid] = acc;
}

// ---- top-64 per (b,f): MSB-first radix-select — FROZEN semantics
__global__ void __launch_bounds__(1024) k_top64(const float* __restrict__ mag,
                                                int* __restrict__ top) {
  int bf = blockIdx.x;
  const float* m = mag + (long long)bf * SEG;
  int tid = threadIdx.x;
  __shared__ u32 bins[256];
  __shared__ u64 sel[64];
  __shared__ u32 tie[2048];
  __shared__ u32 scal[4];

  u32 enc[64];
#pragma unroll
  for (int k = 0; k < 64; ++k) enc[k] = encf(m[tid + (k << 10)]);

  u32 prefix = 0u, need = 64u;
  for (int pass = 0; pass < 4; ++pass) {
    int shift = 24 - pass * 8;
    if (tid < 256) bins[tid] = 0u;
    __syncthreads();
#pragma unroll
    for (int k = 0; k < 64; ++k) {
      u32 e = enc[k];
      bool ok = (pass == 0) || ((e >> (shift + 8)) == (prefix >> (shift + 8)));
      if (ok) atomicAdd(&bins[(e >> shift) & 0xFFu], 1u);
    }
    __syncthreads();
    if (tid == 0) {
      u32 cum = 0; int d = 255;
      for (; d >= 0; --d) {
        u32 c = bins[d];
        if (cum + c >= need) break;
        cum += c;
      }
      if (d < 0) d = 0;
      scal[0] = prefix | ((u32)d << shift);
      scal[1] = need - cum;
      scal[2] = 0u; scal[3] = 0u;
    }
    __syncthreads();
    prefix = scal[0]; need = scal[1];
    __syncthreads();
  }

#pragma unroll
  for (int k = 0; k < 64; ++k) {
    u32 e = enc[k];
    int s = tid + (k << 10);
    if (e > prefix) {
      u32 p = atomicAdd(&scal[2], 1u);
      sel[p] = ((u64)e << 32) | (u64)(0xFFFFFFFFu - (u32)s);
    } else if (e == prefix) {
      u32 p = atomicAdd(&scal[3], 1u);
      if (p < 2048u) tie[p] = (u32)s;
    }
  }
  __syncthreads();
  int tc = (int)scal[3];
  int k2 = (int)need;
  for (int i = tid; i < tc; i += 1024) {
    u32 si = tie[i];
    int rank = 0;
    for (int j = 0; j < tc; ++j) rank += (tie[j] < si);
    if (rank < k2) {
      u32 p = atomicAdd(&scal[2], 1u);
      sel[p] = ((u64)prefix << 32) | (u64)(0xFFFFFFFFu - si);
    }
  }
  __syncthreads();
  if (tid < 64) {
    u64 mine = sel[tid];
    int rank = 0;
    for (int j = 0; j < 64; ++j) rank += (sel[j] > mine);
    int s = (int)(0xFFFFFFFFu - (u32)(mine & 0xFFFFFFFFull));
    top[bf * 64 + rank] = s;
  }
}

// ---- centers -> cov -> inv -> maha -> radix-select top-169 -> graph — FROZEN
__global__ void __launch_bounds__(256) k_graph(const int* __restrict__ top,
                                               float* __restrict__ out) {
  int bf = blockIdx.x;
  int tid = threadIdx.x;
  __shared__ float cy[64], cx[64];
  __shared__ float inv[4];
  __shared__ u32 keys[4096];
  __shared__ u32 bins[256];
  __shared__ u32 tie[4096];
  __shared__ u32 scal[4];
  if (tid < 64) {
    int idx = top[bf * 64 + tid];
    cy[tid] = (float)((idx >> 6) * 8 + 4);
    cx[tid] = (float)((idx & 63) * 8 + 4);
  }
  __syncthreads();
  if (tid == 0) {
    float sy = 0.f, sx = 0.f;
    for (int r = 0; r < 64; ++r) sy = __fadd_rn(sy, cy[r]);
    for (int r = 0; r < 64; ++r) sx = __fadd_rn(sx, cx[r]);
    float my = __fdiv_rn(sy, 64.0f), mx = __fdiv_rn(sx, 64.0f);
    float c00 = 0.f, c01 = 0.f, c11 = 0.f;
    for (int r = 0; r < 64; ++r) {
      float dy = __fsub_rn(cy[r], my);
      float dx = __fsub_rn(cx[r], mx);
      c00 = __fadd_rn(c00, __fmul_rn(dy, dy));
      c01 = __fadd_rn(c01, __fmul_rn(dy, dx));
      c11 = __fadd_rn(c11, __fmul_rn(dx, dx));
    }
    c00 = __fdiv_rn(c00, 63.0f); c01 = __fdiv_rn(c01, 63.0f); c11 = __fdiv_rn(c11, 63.0f);
    c00 = __fadd_rn(c00, 1e-6f); c11 = __fadd_rn(c11, 1e-6f);
    double det = (double)c00 * (double)c11 - (double)c01 * (double)c01;
    inv[0] = (float)((double)c11 / det);
    inv[1] = (float)(-(double)c01 / det);
    inv[2] = inv[1];
    inv[3] = (float)((double)c00 / det);
  }
  __syncthreads();
  float i00 = inv[0], i01 = inv[1], i10 = inv[2], i11 = inv[3];
  long long obase = (long long)bf * 4096;
  for (int e = tid; e < 4096; e += 256) {
    int q = e >> 6, r = e & 63;
    float d0 = __fsub_rn(cy[r], cy[q]);
    float d1 = __fsub_rn(cx[r], cx[q]);
    float v0 = __fadd_rn(__fadd_rn(0.0f, __fmul_rn(d0, i00)), __fmul_rn(d1, i10));
    float v1 = __fadd_rn(__fadd_rn(0.0f, __fmul_rn(d0, i01)), __fmul_rn(d1, i11));
    float p0 = __fmul_rn(v0, d0);
    float p1 = __fmul_rn(v1, d1);
    float s0 = __fsqrt_rn(p0);
    float s1 = __fsqrt_rn(p1);
    float mh = __fadd_rn(__fadd_rn(0.0f, s0), s1);
    u32 key;
    if (mh != mh) key = 0xFFFFFFFFu;
    else key = encf(-mh);
    keys[e] = key;
    out[obase + e] = 0.0f;
  }
  __syncthreads();

  u32 prefix = 0u, need = 169u;
  for (int pass = 0; pass < 4; ++pass) {
    int shift = 24 - pass * 8;
    if (tid == 0) { scal[2] = 0u; }
    bins[tid] = 0u;
    __syncthreads();
    for (int k = 0; k < 16; ++k) {
      u32 ky = keys[tid + (k << 8)];
      bool ok = (pass == 0) || ((ky >> (shift + 8)) == (prefix >> (shift + 8)));
      if (ok) atomicAdd(&bins[(ky >> shift) & 0xFFu], 1u);
    }
    __syncthreads();
    if (tid == 0) {
      u32 cum = 0; int d = 255;
      for (; d >= 0; --d) {
        u32 c = bins[d];
        if (cum + c >= need) break;
        cum += c;
      }
      if (d < 0) d = 0;
      scal[0] = prefix | ((u32)d << shift);
      scal[1] = need - cum;
    }
    __syncthreads();
    prefix = scal[0]; need = scal[1];
    __syncthreads();
  }

  for (int k = 0; k < 16; ++k) {
    int e = tid + (k << 8);
    u32 ky = keys[e];
    if (ky > prefix) out[obase + e] = 1.0f;
    else if (ky == prefix) {
      u32 p = atomicAdd(&scal[2], 1u);
      tie[p] = (u32)e;
    }
  }
  __syncthreads();
  int tc = (int)scal[2];
  for (int i = tid; i < tc; i += 256) {
    u32 ei = tie[i];
    int rank = 0;
    for (int j = 0; j < tc; ++j) rank += (tie[j] < ei);
    if (rank < (int)need) out[obase + ei] = 1.0f;
  }
}

extern "C" void kernel_launch(void* const* d_in, const int* in_sizes, int n_in,
                              void* d_out, int out_size, void* d_ws, size_t ws_size,
                              hipStream_t stream) {
  if (ws_size < (size_t)WS_NEED) return;
  const float* x = (const float*)d_in[0];
  float* out = (float*)d_out;
  char* ws = (char*)d_ws;
  u32* mm = (u32*)(ws + WS_MM);
  float* corr = (float*)(ws + WS_CORR);
  u32* hist = (u32*)(ws + WS_HIST);
  int* top = (int*)(ws + WS_TOP);
  float* mag = (float*)(ws + WS_MAG);
  u32* mmpart = (u32*)(ws + WS_MMPART);   // overlaid on mag region
  u32* histc = (u32*)(ws + WS_HISTC);     // overlaid on mag region

  hipLaunchKernelGGL(k_init, dim3(300), dim3(256), 0, stream, histc);
  hipLaunchKernelGGL(k_minmax_pass, dim3(2048), dim3(256), 0, stream, x, mmpart);
  hipLaunchKernelGGL(k_mm_reduce, dim3(4), dim3(256), 0, stream, mmpart, mm);
  hipLaunchKernelGGL(k_hist_pass, dim3(2048), dim3(256), 0, stream, x, mm, histc);
  hipLaunchKernelGGL(k_hist_reduce, dim3(4), dim3(320), 0, stream, histc, hist);
  hipLaunchKernelGGL(k_corr, dim3(1), dim3(64), 0, stream, hist, corr);
  hipLaunchKernelGGL(k_mag, dim3(7168), dim3(256), 0, stream, x, corr, mag);
  hipLaunchKernelGGL(k_top64, dim3(28), dim3(1024), 0, stream, mag, top);
  hipLaunchKernelGGL(k_graph, dim3(28), dim3(256), 0, stream, top, out);
}

// Round 4
// 298.224 us; speedup vs baseline: 5.6065x; 1.3227x over previous
//
#include <hip/hip_runtime.h>
#include <stdint.h>

// ============================================================================
// Motion_Relation_Mining — bit-exact replication of the JAX (CPU) reference.
//
// FROZEN (verified passing R0-R3, absmax 0.0): all f32 op sequences,
// NAN_POLICY_A, FMA-tanh, sequential reduce orders, radix-select semantics.
//
// R2: two-stage reductions replaced contended global atomics.
// R3: k_corr parallelized — hx/hx1 moved from scratch (rule #20: runtime-
//     indexed arrays -> local memory, ~500cy/access at 1-wave occupancy) to
//     LDS; the 200 double-precision logs run 100-wide instead of serially.
//     All sequential f32 add chains preserved on lane 0 (bit-exact).
// ============================================================================

typedef unsigned int u32;
typedef unsigned long long u64;

// sizes
#define BB 4
#define TT 8
#define CC 16
#define HWN 65536              // H*W
#define NF 7
#define FRAME 1048576LL        // C*H*W
#define NELF 7340032.0f        // nf*C*H*W per batch (exact in f32)
#define NPAIR 28
#define SEG 65536

// ws layout (bytes)
#define WS_MM 0                // u32[24] final min/max (encoded)
#define WS_CORR 128            // float[4]
#define WS_HIST 512            // u32[4][300] final histograms
#define WS_TOP 8192            // int[28][64]
#define WS_MAG 16384           // float[28][65536]
// overlaid inside WS_MAG region — fully consumed before k_mag writes:
#define WS_MMPART (WS_MAG)            // u32[2048][6]  = 48 KiB
#define WS_HISTC  (WS_MAG + 65536)    // u32[4][64][300] = 300 KiB
#define WS_NEED (16384 + 28LL*65536*4)

__device__ __forceinline__ u32 encf(float f) {
  u32 u = __float_as_uint(f);
  return (u & 0x80000000u) ? ~u : (u | 0x80000000u);
}
__device__ __forceinline__ float decf(u32 e) {
  u32 u = (e & 0x80000000u) ? (e ^ 0x80000000u) : ~e;
  return __uint_as_float(u);
}

// zero the 64x4 histogram copies (required each call: graph replays)
__global__ void k_init(u32* histc) {
  int i = blockIdx.x * 256 + threadIdx.x;
  if (i < 76800) histc[i] = 0u;
}

// ---- single pass over frames: per-batch min/max of x_t, x_t1, x_t*x_t1.
__global__ void k_minmax_pass(const float* __restrict__ x, u32* __restrict__ part) {
  const int blk = blockIdx.x;            // 2048 blocks: 512 per batch
  const int b = blk >> 9;
  const long long w0 = (long long)(blk & 511) * 2048;
  const int tid = threadIdx.x;
  u32 mn0 = 0xFFFFFFFFu, mx0 = 0u, mn1 = 0xFFFFFFFFu, mx1 = 0u,
      mnp = 0xFFFFFFFFu, mxp = 0u;
  float prev[8];
  for (int t = 0; t < 8; ++t) {
    const float* fp = x + ((long long)(b * TT + t)) * FRAME + w0 + tid;
#pragma unroll
    for (int k = 0; k < 8; ++k) {
      float v = fp[k << 8];
      u32 ev = encf(v);
      if (t < 7) { mn0 = min(mn0, ev); mx0 = max(mx0, ev); }   // x_t view
      if (t > 0) {                                             // x_t1 view + product
        mn1 = min(mn1, ev); mx1 = max(mx1, ev);
        u32 ep = encf(__fmul_rn(prev[k], v));
        mnp = min(mnp, ep); mxp = max(mxp, ep);
      }
      prev[k] = v;
    }
  }
  __shared__ u32 sm[6][256];
  sm[0][tid] = mn0; sm[1][tid] = mx0; sm[2][tid] = mn1;
  sm[3][tid] = mx1; sm[4][tid] = mnp; sm[5][tid] = mxp;
  __syncthreads();
  for (int st = 128; st > 0; st >>= 1) {
    if (tid < st) {
      sm[0][tid] = min(sm[0][tid], sm[0][tid + st]);
      sm[1][tid] = max(sm[1][tid], sm[1][tid + st]);
      sm[2][tid] = min(sm[2][tid], sm[2][tid + st]);
      sm[3][tid] = max(sm[3][tid], sm[3][tid + st]);
      sm[4][tid] = min(sm[4][tid], sm[4][tid + st]);
      sm[5][tid] = max(sm[5][tid], sm[5][tid + st]);
    }
    __syncthreads();
  }
  if (tid == 0) {
    u32* o = part + blk * 6;
    o[0] = sm[0][0]; o[1] = sm[1][0]; o[2] = sm[2][0];
    o[3] = sm[3][0]; o[4] = sm[4][0]; o[5] = sm[5][0];
  }
}

// 4 blocks (one per batch): reduce 512 partials -> mm[b*6..]
__global__ void k_mm_reduce(const u32* __restrict__ part, u32* __restrict__ mm) {
  const int b = blockIdx.x;
  const int tid = threadIdx.x;
  const u32* p0 = part + (b * 512 + tid) * 6;
  const u32* p1 = p0 + 256 * 6;
  __shared__ u32 sm[6][256];
  sm[0][tid] = min(p0[0], p1[0]); sm[1][tid] = max(p0[1], p1[1]);
  sm[2][tid] = min(p0[2], p1[2]); sm[3][tid] = max(p0[3], p1[3]);
  sm[4][tid] = min(p0[4], p1[4]); sm[5][tid] = max(p0[5], p1[5]);
  __syncthreads();
  for (int st = 128; st > 0; st >>= 1) {
    if (tid < st) {
      sm[0][tid] = min(sm[0][tid], sm[0][tid + st]);
      sm[1][tid] = max(sm[1][tid], sm[1][tid + st]);
      sm[2][tid] = min(sm[2][tid], sm[2][tid + st]);
      sm[3][tid] = max(sm[3][tid], sm[3][tid + st]);
      sm[4][tid] = min(sm[4][tid], sm[4][tid + st]);
      sm[5][tid] = max(sm[5][tid], sm[5][tid + st]);
    }
    __syncthreads();
  }
  if (tid == 0)
    for (int i = 0; i < 6; ++i) mm[b * 6 + i] = sm[i][0];
}

__device__ __forceinline__ int bin_of(float v, float vmin, float den) {
  float tt = __fsub_rn(v, vmin);
  float q = __fdiv_rn(tt, den);
  float z = __fmul_rn(q, 100.0f);
  z = fminf(fmaxf(z, 0.0f), 99.0f);
  return (int)z;
}

// ---- single pass over frames: LDS hist -> one of 64 global copies per batch
__global__ void k_hist_pass(const float* __restrict__ x, const u32* __restrict__ mm,
                            u32* __restrict__ histc) {
  __shared__ u32 h[300];
  for (int i = threadIdx.x; i < 300; i += 256) h[i] = 0u;
  __syncthreads();
  const int blk = blockIdx.x;
  const int b = blk >> 9;
  const long long w0 = (long long)(blk & 511) * 2048;
  const int tid = threadIdx.x;
  float mn_t = decf(mm[6 * b + 0]), den_t = __fsub_rn(decf(mm[6 * b + 1]), decf(mm[6 * b + 0]));
  float mn_1 = decf(mm[6 * b + 2]), den_1 = __fsub_rn(decf(mm[6 * b + 3]), decf(mm[6 * b + 2]));
  float mn_p = decf(mm[6 * b + 4]), den_p = __fsub_rn(decf(mm[6 * b + 5]), decf(mm[6 * b + 4]));
  float prev[8];
  for (int t = 0; t < 8; ++t) {
    const float* fp = x + ((long long)(b * TT + t)) * FRAME + w0 + tid;
#pragma unroll
    for (int k = 0; k < 8; ++k) {
      float v = fp[k << 8];
      if (t < 7) atomicAdd(&h[bin_of(v, mn_t, den_t)], 1u);
      if (t > 0) {
        atomicAdd(&h[100 + bin_of(v, mn_1, den_1)], 1u);
        float p = __fmul_rn(prev[k], v);
        atomicAdd(&h[200 + bin_of(p, mn_p, den_p)], 1u);
      }
      prev[k] = v;
    }
  }
  __syncthreads();
  u32* dst = histc + ((b << 6) + (blk & 63)) * 300;
  for (int i = threadIdx.x; i < 300; i += 256) atomicAdd(&dst[i], h[i]);
}

// 4 blocks x 320 threads: hist[b*300+i] = sum of 64 copies (exact integers)
__global__ void k_hist_reduce(const u32* __restrict__ histc, u32* __restrict__ hist) {
  int b = blockIdx.x, i = threadIdx.x;
  if (i < 300) {
    const u32* src = histc + (b << 6) * 300 + i;
    u32 s = 0;
    for (int c = 0; c < 64; ++c) s += src[c * 300];
    hist[b * 300 + i] = s;
  }
}

// Eigen/XLA fast-tanh rational interpolant (FMA form) — FROZEN
__device__ float tanh_emul(float a) {
  const float kClamp = 7.90531110763549805f;
  float xx = fminf(fmaxf(a, -kClamp), kClamp);
  float x2 = __fmul_rn(xx, xx);
  float p = __fmaf_rn(x2, -2.76076847742355e-16f, 2.00018790482477e-13f);
  p = __fmaf_rn(x2, p, -8.60467152213735e-11f);
  p = __fmaf_rn(x2, p, 5.12229709037114e-08f);
  p = __fmaf_rn(x2, p, 1.48572235717979e-05f);
  p = __fmaf_rn(x2, p, 6.37261928875436e-04f);
  p = __fmaf_rn(x2, p, 4.89352455891786e-03f);
  p = __fmul_rn(xx, p);
  float q = __fmaf_rn(x2, 1.19825839466702e-06f, 1.18534705686654e-04f);
  q = __fmaf_rn(x2, q, 2.26843463243900e-03f);
  q = __fmaf_rn(x2, q, 4.89352518554385e-03f);
  float r = __fdiv_rn(p, q);
  if (fabsf(a) < 0.0004f) r = a;
  return r;
}

// ---- mi + corr per batch. R3: parallel per-bin terms (identical op
// sequences), FROZEN sequential add chains on lane 0, LDS not scratch.
__global__ void __launch_bounds__(128) k_corr(const u32* __restrict__ hist,
                                              float* __restrict__ corr) {
  const int b = blockIdx.x;
  const int tid = threadIdx.x;
  __shared__ float shx[100], shx1[100], sterm[100];
  __shared__ float ssum[3];        // Sj, Sx, Sx1
  const u32* HX = hist + b * 300;
  const u32* HX1 = HX + 100;
  const u32* HJ = HX + 200;

  if (tid < 100) {
    shx[tid] = __fdiv_rn((float)HX[tid], NELF);    // same op as before
    shx1[tid] = __fdiv_rn((float)HX1[tid], NELF);
  }
  __syncthreads();
  if (tid == 0) {
    // FROZEN sequential chains (bit-exact order)
    float Sj = 0.0f;
    for (int i = 0; i < 100; ++i) Sj = __fadd_rn(Sj, (float)HJ[i]);
    float Sx = 0.0f, Sx1 = 0.0f;
    for (int i = 0; i < 100; ++i) Sx = __fadd_rn(Sx, shx[i]);
    for (int i = 0; i < 100; ++i) Sx1 = __fadd_rn(Sx1, shx1[i]);
    ssum[0] = Sj; ssum[1] = Sx; ssum[2] = Sx1;
  }
  __syncthreads();
  if (tid < 100) {
    float Sj = ssum[0], Sx = ssum[1], Sx1 = ssum[2];
    float pj = __fdiv_rn((float)HJ[tid], Sj);
    float px = __fdiv_rn(shx[tid], Sx);
    float px1 = __fdiv_rn(shx1[tid], Sx1);
    float la = (float)log((double)__fadd_rn(pj, 1e-10f));
    float lb = (float)log((double)__fadd_rn(__fmul_rn(px, px1), 1e-10f));
    sterm[tid] = __fmul_rn(pj, __fsub_rn(la, lb));
  }
  __syncthreads();
  if (tid == 0) {
    float mi = 0.0f;
    for (int i = 0; i < 100; ++i) mi = __fadd_rn(mi, sterm[i]);  // FROZEN order
    float lm = (float)log((double)mi);
    float th = tanh_emul(lm);
    float num = (float)exp(0.8);
    corr[b] = __fdiv_rn(num, th);
  }
}

// ---- mag[b,f,s] = sequential f32 sum over c of fl(fl(x1-x0)+corr[b]) — FROZEN
__global__ void k_mag(const float* __restrict__ x, const float* __restrict__ corr,
                      float* __restrict__ mag) {
  int gid = blockIdx.x * 256 + threadIdx.x;
  int bf = gid >> 16;
  int s = gid & 65535;
  int b = bf / NF, f = bf % NF;
  int g = s >> 6, i = (s >> 3) & 7, j = s & 7;
  int gy = g >> 5, gx = g & 31;
  int hw = (gy * 8 + i) * 256 + gx * 8 + j;
  const float cb = corr[b];
  long long base = ((long long)(b * TT + f)) * FRAME + hw;
  float acc = 0.0f;
  for (int c = 0; c < CC; ++c) {
    float a0 = x[base + (long long)c * HWN];
    float a1 = x[base + FRAME + (long long)c * HWN];
    acc = __fadd_rn(acc, __fadd_rn(__fsub_rn(a1, a0), cb));
  }
  mag[gid] = acc;
}

// ---- top-64 per (b,f): MSB-first radix-select — FROZEN semantics
__global__ void __launch_bounds__(1024) k_top64(const float* __restrict__ mag,
                                                int* __restrict__ top) {
  int bf = blockIdx.x;
  const float* m = mag + (long long)bf * SEG;
  int tid = threadIdx.x;
  __shared__ u32 bins[256];
  __shared__ u64 sel[64];
  __shared__ u32 tie[2048];
  __shared__ u32 scal[4];

  u32 enc[64];
#pragma unroll
  for (int k = 0; k < 64; ++k) enc[k] = encf(m[tid + (k << 10)]);

  u32 prefix = 0u, need = 64u;
  for (int pass = 0; pass < 4; ++pass) {
    int shift = 24 - pass * 8;
    if (tid < 256) bins[tid] = 0u;
    __syncthreads();
#pragma unroll
    for (int k = 0; k < 64; ++k) {
      u32 e = enc[k];
      bool ok = (pass == 0) || ((e >> (shift + 8)) == (prefix >> (shift + 8)));
      if (ok) atomicAdd(&bins[(e >> shift) & 0xFFu], 1u);
    }
    __syncthreads();
    if (tid == 0) {
      u32 cum = 0; int d = 255;
      for (; d >= 0; --d) {
        u32 c = bins[d];
        if (cum + c >= need) break;
        cum += c;
      }
      if (d < 0) d = 0;
      scal[0] = prefix | ((u32)d << shift);
      scal[1] = need - cum;
      scal[2] = 0u; scal[3] = 0u;
    }
    __syncthreads();
    prefix = scal[0]; need = scal[1];
    __syncthreads();
  }

#pragma unroll
  for (int k = 0; k < 64; ++k) {
    u32 e = enc[k];
    int s = tid + (k << 10);
    if (e > prefix) {
      u32 p = atomicAdd(&scal[2], 1u);
      sel[p] = ((u64)e << 32) | (u64)(0xFFFFFFFFu - (u32)s);
    } else if (e == prefix) {
      u32 p = atomicAdd(&scal[3], 1u);
      if (p < 2048u) tie[p] = (u32)s;
    }
  }
  __syncthreads();
  int tc = (int)scal[3];
  int k2 = (int)need;
  for (int i = tid; i < tc; i += 1024) {
    u32 si = tie[i];
    int rank = 0;
    for (int j = 0; j < tc; ++j) rank += (tie[j] < si);
    if (rank < k2) {
      u32 p = atomicAdd(&scal[2], 1u);
      sel[p] = ((u64)prefix << 32) | (u64)(0xFFFFFFFFu - si);
    }
  }
  __syncthreads();
  if (tid < 64) {
    u64 mine = sel[tid];
    int rank = 0;
    for (int j = 0; j < 64; ++j) rank += (sel[j] > mine);
    int s = (int)(0xFFFFFFFFu - (u32)(mine & 0xFFFFFFFFull));
    top[bf * 64 + rank] = s;
  }
}

// ---- centers -> cov -> inv -> maha -> radix-select top-169 -> graph — FROZEN
__global__ void __launch_bounds__(256) k_graph(const int* __restrict__ top,
                                               float* __restrict__ out) {
  int bf = blockIdx.x;
  int tid = threadIdx.x;
  __shared__ float cy[64], cx[64];
  __shared__ float inv[4];
  __shared__ u32 keys[4096];
  __shared__ u32 bins[256];
  __shared__ u32 tie[4096];
  __shared__ u32 scal[4];
  if (tid < 64) {
    int idx = top[bf * 64 + tid];
    cy[tid] = (float)((idx >> 6) * 8 + 4);
    cx[tid] = (float)((idx & 63) * 8 + 4);
  }
  __syncthreads();
  if (tid == 0) {
    float sy = 0.f, sx = 0.f;
    for (int r = 0; r < 64; ++r) sy = __fadd_rn(sy, cy[r]);
    for (int r = 0; r < 64; ++r) sx = __fadd_rn(sx, cx[r]);
    float my = __fdiv_rn(sy, 64.0f), mx = __fdiv_rn(sx, 64.0f);
    float c00 = 0.f, c01 = 0.f, c11 = 0.f;
    for (int r = 0; r < 64; ++r) {
      float dy = __fsub_rn(cy[r], my);
      float dx = __fsub_rn(cx[r], mx);
      c00 = __fadd_rn(c00, __fmul_rn(dy, dy));
      c01 = __fadd_rn(c01, __fmul_rn(dy, dx));
      c11 = __fadd_rn(c11, __fmul_rn(dx, dx));
    }
    c00 = __fdiv_rn(c00, 63.0f); c01 = __fdiv_rn(c01, 63.0f); c11 = __fdiv_rn(c11, 63.0f);
    c00 = __fadd_rn(c00, 1e-6f); c11 = __fadd_rn(c11, 1e-6f);
    double det = (double)c00 * (double)c11 - (double)c01 * (double)c01;
    inv[0] = (float)((double)c11 / det);
    inv[1] = (float)(-(double)c01 / det);
    inv[2] = inv[1];
    inv[3] = (float)((double)c00 / det);
  }
  __syncthreads();
  float i00 = inv[0], i01 = inv[1], i10 = inv[2], i11 = inv[3];
  long long obase = (long long)bf * 4096;
  for (int e = tid; e < 4096; e += 256) {
    int q = e >> 6, r = e & 63;
    float d0 = __fsub_rn(cy[r], cy[q]);
    float d1 = __fsub_rn(cx[r], cx[q]);
    float v0 = __fadd_rn(__fadd_rn(0.0f, __fmul_rn(d0, i00)), __fmul_rn(d1, i10));
    float v1 = __fadd_rn(__fadd_rn(0.0f, __fmul_rn(d0, i01)), __fmul_rn(d1, i11));
    float p0 = __fmul_rn(v0, d0);
    float p1 = __fmul_rn(v1, d1);
    float s0 = __fsqrt_rn(p0);
    float s1 = __fsqrt_rn(p1);
    float mh = __fadd_rn(__fadd_rn(0.0f, s0), s1);
    u32 key;
    if (mh != mh) key = 0xFFFFFFFFu;
    else key = encf(-mh);
    keys[e] = key;
    out[obase + e] = 0.0f;
  }
  __syncthreads();

  u32 prefix = 0u, need = 169u;
  for (int pass = 0; pass < 4; ++pass) {
    int shift = 24 - pass * 8;
    if (tid == 0) { scal[2] = 0u; }
    bins[tid] = 0u;
    __syncthreads();
    for (int k = 0; k < 16; ++k) {
      u32 ky = keys[tid + (k << 8)];
      bool ok = (pass == 0) || ((ky >> (shift + 8)) == (prefix >> (shift + 8)));
      if (ok) atomicAdd(&bins[(ky >> shift) & 0xFFu], 1u);
    }
    __syncthreads();
    if (tid == 0) {
      u32 cum = 0; int d = 255;
      for (; d >= 0; --d) {
        u32 c = bins[d];
        if (cum + c >= need) break;
        cum += c;
      }
      if (d < 0) d = 0;
      scal[0] = prefix | ((u32)d << shift);
      scal[1] = need - cum;
    }
    __syncthreads();
    prefix = scal[0]; need = scal[1];
    __syncthreads();
  }

  for (int k = 0; k < 16; ++k) {
    int e = tid + (k << 8);
    u32 ky = keys[e];
    if (ky > prefix) out[obase + e] = 1.0f;
    else if (ky == prefix) {
      u32 p = atomicAdd(&scal[2], 1u);
      tie[p] = (u32)e;
    }
  }
  __syncthreads();
  int tc = (int)scal[2];
  for (int i = tid; i < tc; i += 256) {
    u32 ei = tie[i];
    int rank = 0;
    for (int j = 0; j < tc; ++j) rank += (tie[j] < ei);
    if (rank < (int)need) out[obase + ei] = 1.0f;
  }
}

extern "C" void kernel_launch(void* const* d_in, const int* in_sizes, int n_in,
                              void* d_out, int out_size, void* d_ws, size_t ws_size,
                              hipStream_t stream) {
  if (ws_size < (size_t)WS_NEED) return;
  const float* x = (const float*)d_in[0];
  float* out = (float*)d_out;
  char* ws = (char*)d_ws;
  u32* mm = (u32*)(ws + WS_MM);
  float* corr = (float*)(ws + WS_CORR);
  u32* hist = (u32*)(ws + WS_HIST);
  int* top = (int*)(ws + WS_TOP);
  float* mag = (float*)(ws + WS_MAG);
  u32* mmpart = (u32*)(ws + WS_MMPART);
  u32* histc = (u32*)(ws + WS_HISTC);

  hipLaunchKernelGGL(k_init, dim3(300), dim3(256), 0, stream, histc);
  hipLaunchKernelGGL(k_minmax_pass, dim3(2048), dim3(256), 0, stream, x, mmpart);
  hipLaunchKernelGGL(k_mm_reduce, dim3(4), dim3(256), 0, stream, mmpart, mm);
  hipLaunchKernelGGL(k_hist_pass, dim3(2048), dim3(256), 0, stream, x, mm, histc);
  hipLaunchKernelGGL(k_hist_reduce, dim3(4), dim3(320), 0, stream, histc, hist);
  hipLaunchKernelGGL(k_corr, dim3(4), dim3(128), 0, stream, hist, corr);
  hipLaunchKernelGGL(k_mag, dim3(7168), dim3(256), 0, stream, x, corr, mag);
  hipLaunchKernelGGL(k_top64, dim3(28), dim3(1024), 0, stream, mag, top);
  hipLaunchKernelGGL(k_graph, dim3(28), dim3(256), 0, stream, top, out);
}